// Round 2
// baseline (148.582 us; speedup 1.0000x reference)
//
#include <hip/hip_runtime.h>
#include <math.h>

// Problem constants (from reference setup_inputs)
#define NQ 2048
#define NB 8192
#define DIM 32

// Tiling
#define TPB 256                  // threads per block
#define BPT 2                    // backgrounds per thread (adjacent -> float2 r loads)
#define BG_PER_BLOCK (TPB * BPT) // 512
#define QTILE 32                 // queries per block

#define LOG2E 1.44269504088896340736f

// Force a value to be materialized in a VGPR here (defeats load-sinking).
#define PIN(x) asm volatile("" : "+v"(x))

// grid = (NB/BG_PER_BLOCK = 16, NQ/QTILE = 64) = 1024 blocks, 4 waves each
// -> 4 blocks/CU, 16 waves/CU.
__global__ __launch_bounds__(TPB) void relnw_partial(
    const float* __restrict__ xb,     // (NB, DIM)
    const float* __restrict__ yb,     // (NB,)
    const float* __restrict__ xq,     // (NQ, DIM)
    const float* __restrict__ r,      // (NQ, NB)
    const float* __restrict__ sigma,  // (1,)
    const float* __restrict__ rscale, // (1,)
    const float* __restrict__ w,      // (DIM,)
    float* __restrict__ acc)          // ws: [0:NQ] = sum_k, [NQ:2NQ] = sum_k*y
{
    __shared__ float sq2[QTILE];

    const int tid = threadIdx.x;
    const int b0  = blockIdx.x * BG_PER_BLOCK + tid * BPT;
    const int q0  = blockIdx.y * QTILE;

    const float c1 = -LOG2E / sigma[0];      // coeff on dist (log2 space)
    const float c2 =  LOG2E * rscale[0];     // coeff on r    (log2 space)

    // Load this thread's backgrounds: xb2w[d] = xb[d]*w[d]^2 (w^2 folded into
    // background side so the query row can be used raw from scalar loads).
    float xb2w[BPT][DIM];
    float b2[BPT], yv[BPT];
#pragma unroll
    for (int j = 0; j < BPT; ++j) {
        const float4* row = (const float4*)(xb + (size_t)(b0 + j) * DIM);
        float s = 0.f;
#pragma unroll
        for (int v = 0; v < DIM / 4; ++v) {
            float4 x4 = row[v];
            float xs[4] = {x4.x, x4.y, x4.z, x4.w};
#pragma unroll
            for (int c = 0; c < 4; ++c) {
                int d = v * 4 + c;
                float wv = w[d];              // uniform -> s_load
                float t  = xs[c] * wv;        // (xb*w)
                s        = fmaf(t, t, s);     // b2 = sum (xb*w)^2
                xb2w[j][d] = t * wv;          // xb*w^2
            }
        }
        b2[j] = s;
        yv[j] = yb[b0 + j];
    }
    // Pin the whole background tile in VGPRs: round-1 showed VGPR_Count=44,
    // i.e. the compiler sank these loads into the q-loop (re-loading 64 floats
    // per query iteration). Keep them resident.
#pragma unroll
    for (int j = 0; j < BPT; ++j) {
#pragma unroll
        for (int d = 0; d < DIM; ++d) PIN(xb2w[j][d]);
        PIN(b2[j]);
        PIN(yv[j]);
    }

    // q2 for this block's query tile: q2 = sum (xq*w)^2
    if (tid < QTILE) {
        const float* row = xq + (size_t)(q0 + tid) * DIM;
        float s = 0.f;
#pragma unroll
        for (int d = 0; d < DIM; ++d) {
            float t = row[d] * w[d];
            s = fmaf(t, t, s);
        }
        sq2[tid] = s;
    }
    __syncthreads();

    const float* rp = r + (size_t)q0 * NB + b0;
    float2 rv = *(const float2*)rp;          // prefetch qi=0

    for (int qi = 0; qi < QTILE; ++qi) {
        const float2 rv_cur = rv;
        if (qi + 1 < QTILE)                  // prefetch next iteration's r
            rv = *(const float2*)(rp + (size_t)(qi + 1) * NB);

        const float* xqr = xq + (size_t)(q0 + qi) * DIM;  // wave-uniform -> s_load
        const float q2 = sq2[qi];

        float sk = 0.f, sky = 0.f;
#pragma unroll
        for (int j = 0; j < BPT; ++j) {
            // 2-way split accumulators: halve the FMA dependency chain
            float a0 = 0.f, a1 = 0.f;
#pragma unroll
            for (int d = 0; d < DIM; d += 2) {
                a0 = fmaf(xqr[d],     xb2w[j][d],     a0);
                a1 = fmaf(xqr[d + 1], xb2w[j][d + 1], a1);
            }
            float dot = a0 + a1;
            float d2 = fmaf(-2.f, dot, q2 + b2[j]);
            d2 = fmaxf(d2, 0.f);
            float dist = __builtin_amdgcn_sqrtf(d2);
            float rj = (j == 0) ? rv_cur.x : rv_cur.y;
            float e = fmaf(dist, c1, rj * c2);         // log2-space exponent
            float k = __builtin_amdgcn_exp2f(e);
            sk += k;
            sky = fmaf(k, yv[j], sky);
        }

        // 5-level butterfly (all intra-32-lane -> ds_swizzle), then lanes 0
        // and 32 each hold a 32-lane half-sum; both issue the atomic.
#pragma unroll
        for (int off = 1; off <= 16; off <<= 1) {
            sk  += __shfl_xor(sk,  off, 64);
            sky += __shfl_xor(sky, off, 64);
        }
        if ((tid & 31) == 0) {
            atomicAdd(acc + (q0 + qi),      sk);
            atomicAdd(acc + NQ + (q0 + qi), sky);
        }
    }
}

__global__ __launch_bounds__(256) void relnw_finalize(
    const float* __restrict__ acc, float* __restrict__ out)
{
    int q = blockIdx.x * 256 + threadIdx.x;
    if (q < NQ)
        out[q] = acc[NQ + q] / (acc[q] + 1e-8f);
}

extern "C" void kernel_launch(void* const* d_in, const int* in_sizes, int n_in,
                              void* d_out, int out_size, void* d_ws, size_t ws_size,
                              hipStream_t stream) {
    const float* xb     = (const float*)d_in[0]; // (8192,32)
    const float* yb     = (const float*)d_in[1]; // (8192,)
    const float* xq     = (const float*)d_in[2]; // (2048,32)
    const float* r      = (const float*)d_in[3]; // (2048,8192)
    const float* sigma  = (const float*)d_in[4]; // (1,)
    const float* rscale = (const float*)d_in[5]; // (1,)
    const float* w      = (const float*)d_in[6]; // (32,)
    float* out = (float*)d_out;
    float* acc = (float*)d_ws;                   // 2*NQ floats = 16 KB

    // ws is poisoned 0xAA before every timed launch -> zero the accumulators
    hipMemsetAsync(acc, 0, 2 * NQ * sizeof(float), stream);

    dim3 grid(NB / BG_PER_BLOCK, NQ / QTILE);    // (16, 64)
    relnw_partial<<<grid, TPB, 0, stream>>>(xb, yb, xq, r, sigma, rscale, w, acc);
    relnw_finalize<<<(NQ + 255) / 256, 256, 0, stream>>>(acc, out);
}

// Round 3
// 117.030 us; speedup vs baseline: 1.2696x; 1.2696x over previous
//
#include <hip/hip_runtime.h>
#include <math.h>

// Problem constants (from reference setup_inputs)
#define NQ 2048
#define NB 8192
#define DIM 32

#define LOG2E 1.44269504088896340736f

typedef _Float16 half8 __attribute__((ext_vector_type(8)));
typedef float    f32x4 __attribute__((ext_vector_type(4)));

// ---------------- workspace layout (bytes) ----------------
// acc  : 2*NQ f32      @ 0        (16384)
// q2   : NQ   f32      @ 16384    (8192)
// b2   : NB   f32      @ 24576    (32768)
// XQh  : NQ*DIM f16    @ 57344    (131072)
// XBh  : NB*DIM f16    @ 188416   (524288)   -> total 712704 bytes
#define WS_ACC 0
#define WS_Q2  16384
#define WS_B2  24576
#define WS_XQH 57344
#define WS_XBH 188416

// Convert x*w to f16 and compute row norms FROM THE ROUNDED VALUES, so the
// MFMA-computed d2 = ||Aq - Ab||^2 has no representation-mismatch cancellation.
__global__ __launch_bounds__(256) void relnw_pre(
    const float* __restrict__ xq, const float* __restrict__ xb,
    const float* __restrict__ w,
    _Float16* __restrict__ XQh, _Float16* __restrict__ XBh,
    float* __restrict__ q2, float* __restrict__ b2)
{
    int i = blockIdx.x * 256 + threadIdx.x;
    const float* src; _Float16* dst; float* s2;
    if (i < NQ)            { src = xq + (size_t)i * DIM;        dst = XQh + (size_t)i * DIM;        s2 = q2 + i; }
    else if (i < NQ + NB)  { int j = i - NQ;
                             src = xb + (size_t)j * DIM;        dst = XBh + (size_t)j * DIM;        s2 = b2 + j; }
    else return;
    float s = 0.f;
#pragma unroll
    for (int d = 0; d < DIM; ++d) {
        float t = src[d] * w[d];       // w uniform -> s_load
        _Float16 h = (_Float16)t;
        float th = (float)h;
        s = fmaf(th, th, s);
        dst[d] = h;
    }
    *s2 = s;
}

// Main kernel: grid (8, 128), 256 threads (4 waves).
// Wave task: q-tile of 16 queries (blockIdx.y), bg-chunk of 256 backgrounds
// (chunk id = blockIdx.x*4 + wave), processed as 16 MFMA tiles of 16 bgs.
// One v_mfma_f32_16x16x32_f16 per tile computes all 256 dots (K=32=DIM).
// C/D layout: col = lane&15 (bg), row = (lane>>4)*4 + reg (query).
// A/B frags: lane holds 8 contiguous k-elements at k0=(lane>>4)*8 of row
// (lane&15) -> one 16B load each, fully coalesced.
#define BT_PER_WAVE 16
#define BG_PER_WAVE (BT_PER_WAVE * 16)   // 256

__global__ __launch_bounds__(256) void relnw_main(
    const _Float16* __restrict__ XQh,  // (NQ, DIM)
    const _Float16* __restrict__ XBh,  // (NB, DIM)
    const float* __restrict__ q2,      // (NQ,)
    const float* __restrict__ b2,      // (NB,)
    const float* __restrict__ yb,      // (NB,)
    const float* __restrict__ r,       // (NQ, NB)
    const float* __restrict__ sigma,   // (1,)
    const float* __restrict__ rscale,  // (1,)
    float* __restrict__ acc)           // [0:NQ]=sum_k, [NQ:2NQ]=sum_k*y
{
    const int tid  = threadIdx.x;
    const int lane = tid & 63;
    const int wid  = tid >> 6;
    const int m    = lane & 15;   // A row (query) / B col (bg) / C col (bg)
    const int quad = lane >> 4;   // 0..3

    const int q0     = blockIdx.y * 16;
    const int bstart = (blockIdx.x * 4 + wid) * BG_PER_WAVE;

    const float c1 = -LOG2E / sigma[0];   // coeff on dist (log2 space)
    const float c2 =  LOG2E * rscale[0];  // coeff on r

    // A fragment for this wave's 16 queries (fixed across the b-loop)
    const half8 afrag = *(const half8*)(XQh + (size_t)(q0 + m) * DIM + quad * 8);

    // q2 for this lane's 4 C-rows (queries q0 + quad*4 + g)
    float q2r[4];
#pragma unroll
    for (int g = 0; g < 4; ++g) q2r[g] = q2[q0 + quad * 4 + g];

    const _Float16* xbp = XBh + (size_t)(bstart + m) * DIM + quad * 8;
    const float*    rp  = r + (size_t)(q0 + quad * 4) * NB + bstart + m;

    float sk[4]  = {0.f, 0.f, 0.f, 0.f};
    float sky[4] = {0.f, 0.f, 0.f, 0.f};

#pragma unroll
    for (int it = 0; it < BT_PER_WAVE; ++it) {
        const int bc = bstart + it * 16 + m;            // this lane's bg col
        const half8 bfrag = *(const half8*)(xbp + (size_t)it * 16 * DIM);
        const float yv  = yb[bc];
        const float b2v = b2[bc];
        float rr[4];
#pragma unroll
        for (int g = 0; g < 4; ++g) rr[g] = rp[(size_t)g * NB + it * 16];

        f32x4 dot = __builtin_amdgcn_mfma_f32_16x16x32_f16(
            afrag, bfrag, (f32x4){0.f, 0.f, 0.f, 0.f}, 0, 0, 0);

#pragma unroll
        for (int g = 0; g < 4; ++g) {
            float d2 = fmaf(-2.f, dot[g], q2r[g] + b2v);
            d2 = fmaxf(d2, 0.f);
            float dist = __builtin_amdgcn_sqrtf(d2);
            float e = fmaf(dist, c1, rr[g] * c2);       // log2-space exponent
            float k = __builtin_amdgcn_exp2f(e);
            sk[g] += k;
            sky[g] = fmaf(k, yv, sky[g]);
        }
    }

    // Reduce across the 16 bg-columns (low 4 lane bits), once per wave.
#pragma unroll
    for (int off = 1; off <= 8; off <<= 1) {
#pragma unroll
        for (int g = 0; g < 4; ++g) {
            sk[g]  += __shfl_xor(sk[g],  off, 64);
            sky[g] += __shfl_xor(sky[g], off, 64);
        }
    }
    if (m == 0) {
#pragma unroll
        for (int g = 0; g < 4; ++g) {
            atomicAdd(acc + (q0 + quad * 4 + g),      sk[g]);
            atomicAdd(acc + NQ + (q0 + quad * 4 + g), sky[g]);
        }
    }
}

__global__ __launch_bounds__(256) void relnw_finalize(
    const float* __restrict__ acc, float* __restrict__ out)
{
    int q = blockIdx.x * 256 + threadIdx.x;
    if (q < NQ)
        out[q] = acc[NQ + q] / (acc[q] + 1e-8f);
}

extern "C" void kernel_launch(void* const* d_in, const int* in_sizes, int n_in,
                              void* d_out, int out_size, void* d_ws, size_t ws_size,
                              hipStream_t stream) {
    const float* xb     = (const float*)d_in[0]; // (8192,32)
    const float* yb     = (const float*)d_in[1]; // (8192,)
    const float* xq     = (const float*)d_in[2]; // (2048,32)
    const float* r      = (const float*)d_in[3]; // (2048,8192)
    const float* sigma  = (const float*)d_in[4]; // (1,)
    const float* rscale = (const float*)d_in[5]; // (1,)
    const float* w      = (const float*)d_in[6]; // (32,)
    float* out = (float*)d_out;

    char* ws = (char*)d_ws;
    float*    acc = (float*)(ws + WS_ACC);
    float*    q2  = (float*)(ws + WS_Q2);
    float*    b2  = (float*)(ws + WS_B2);
    _Float16* XQh = (_Float16*)(ws + WS_XQH);
    _Float16* XBh = (_Float16*)(ws + WS_XBH);

    // ws is poisoned 0xAA before every timed launch -> zero the accumulators
    hipMemsetAsync(acc, 0, 2 * NQ * sizeof(float), stream);

    relnw_pre<<<(NQ + NB + 255) / 256, 256, 0, stream>>>(xq, xb, w, XQh, XBh, q2, b2);

    dim3 grid(NB / (4 * BG_PER_WAVE), NQ / 16);  // (8, 128) = 1024 blocks
    relnw_main<<<grid, 256, 0, stream>>>(XQh, XBh, q2, b2, yb, r, sigma, rscale, acc);

    relnw_finalize<<<(NQ + 255) / 256, 256, 0, stream>>>(acc, out);
}